// Round 5
// baseline (1012.043 us; speedup 1.0000x reference)
//
#include <hip/hip_runtime.h>
#include <math.h>

// ImplicitFlowDecoder round 5: f16 MFMA megakernel + software-pipelined weight stream.
// Round-5 changes vs round 4:
//   * gemmT/gemmRegB: weight fragments double-buffered in registers, prefetched one
//     k-step ahead (compiler stopped at 128 VGPRs and left loads latency-exposed;
//     MfmaUtil was 9% with both pipes idle -> latency-bound on L2 weight loads).
//   * gelu: branch-free Abramowitz-Stegun erf polynomial (|err|<=1.5e-7), cheaper
//     than libm erff; f16 storage rounding (5e-4) dominates.

typedef _Float16 half8 __attribute__((ext_vector_type(8)));
typedef _Float16 half4v __attribute__((ext_vector_type(4)));
typedef _Float16 half2v __attribute__((ext_vector_type(2)));
typedef float floatx4 __attribute__((ext_vector_type(4)));

#define NPOINTS_TOTAL (2 * 384 * 512)
#define PPB 128
#define NBLOCKS (NPOINTS_TOTAL / PPB)
#define PTS_PER_IMG 196608

#define WS_CTX   0
#define WS_F1W1  8192
#define WS_F1W2  40960
#define WS_S8    73728
#define WS_F2W1  90112
#define WS_F2W2  122880
#define WS_HW1   155648
#define WS_HW2   221184
#define WS_HW3   253952

__device__ __forceinline__ float sigmoidf_(float x) { return 1.0f / (1.0f + expf(-x)); }
// exact-form gelu via A-S 7.1.26 erf approximation (abs err <= 1.5e-7)
__device__ __forceinline__ float geluf_(float x) {
    const float ax = fabsf(x) * 0.70710678118654752f;
    const float t = 1.0f / fmaf(0.3275911f, ax, 1.0f);
    float poly = fmaf(t, 1.061405429f, -1.453152027f);
    poly = fmaf(t, poly, 1.421413741f);
    poly = fmaf(t, poly, -0.284496736f);
    poly = fmaf(t, poly, 0.254829592f);
    poly *= t;
    float er = 1.0f - poly * expf(-ax * ax);
    er = copysignf(er, x);
    return 0.5f * x * (1.0f + er);
}
__device__ __forceinline__ int swz(int pt) { return (pt & 15) << 3; }

// ---------------- prepack: W[K][N] fp32 -> f16 fragments -------------------
__global__ void prepack_kernel(const float* __restrict__ ctx_w, const float* __restrict__ f1w1,
                               const float* __restrict__ f1w2, const float* __restrict__ s8w,
                               const float* __restrict__ f2w1, const float* __restrict__ f2w2,
                               const float* __restrict__ hw1, const float* __restrict__ hw2,
                               const float* __restrict__ hw3, _Float16* __restrict__ ws) {
    const int bid = blockIdx.x;
    const int lane = threadIdx.x;
    const float* src; int N, CT, start; size_t ofsH;
    if (bid < 16)       { src = ctx_w; N = 128; CT = 8;  start = 0;   ofsH = WS_CTX; }
    else if (bid < 80)  { src = f1w1;  N = 256; CT = 16; start = 16;  ofsH = WS_F1W1; }
    else if (bid < 144) { src = f1w2;  N = 128; CT = 8;  start = 80;  ofsH = WS_F1W2; }
    else if (bid < 176) { src = s8w;   N = 128; CT = 8;  start = 144; ofsH = WS_S8; }
    else if (bid < 240) { src = f2w1;  N = 256; CT = 16; start = 176; ofsH = WS_F2W1; }
    else if (bid < 304) { src = f2w2;  N = 128; CT = 8;  start = 240; ofsH = WS_F2W2; }
    else if (bid < 432) { src = hw1;   N = 256; CT = 16; start = 304; ofsH = WS_HW1; }
    else if (bid < 496) { src = hw2;   N = 128; CT = 8;  start = 432; ofsH = WS_HW2; }
    else                { src = hw3;   N = 64;  CT = 4;  start = 496; ofsH = WS_HW3; }
    const int ti = bid - start;
    const int ks = ti / CT, ct = ti % CT;
    const int m = lane & 15, g = lane >> 4;
    const int kb = ks * 32 + g * 8;
    const int n = ct * 16 + m;
    half8 v;
#pragma unroll
    for (int j = 0; j < 8; ++j) v[j] = (_Float16)src[(size_t)(kb + j) * N + n];
    *reinterpret_cast<half8*>(ws + ofsH + (size_t)ti * 512 + lane * 8) = v;
}

// ---------------- GEMM cores (weight-prefetch pipelined) -------------------
template <int KS, int CT>
__device__ __forceinline__ void gemmT(floatx4 (&acc)[CT][2], const _Float16* __restrict__ wp,
                                      int cts, int ks0, int ct0,
                                      const _Float16* sact, int ptb, int lane) {
    const int m = lane & 15, g = lane >> 4;
    const int pt0 = ptb + m, pt1 = pt0 + 16;
    const int s0 = swz(pt0), s1 = swz(pt1);
    const _Float16* wbase = wp + ((size_t)(ks0 * cts + ct0) << 9) + lane * 8;
    half8 wreg[2][CT];
#pragma unroll
    for (int ct = 0; ct < CT; ++ct)
        wreg[0][ct] = *reinterpret_cast<const half8*>(wbase + ((size_t)ct << 9));
#pragma unroll
    for (int ks = 0; ks < KS; ++ks) {
        if (ks + 1 < KS) {   // prefetch next k-step's weights while this one computes
            const _Float16* wk = wbase + ((size_t)((ks + 1) * cts) << 9);
#pragma unroll
            for (int ct = 0; ct < CT; ++ct)
                wreg[(ks + 1) & 1][ct] = *reinterpret_cast<const half8*>(wk + ((size_t)ct << 9));
        }
        const int k0 = ks * 32 + g * 8;
        half8 a0 = *reinterpret_cast<const half8*>(sact + pt0 * 128 + (k0 ^ s0));
        half8 a1 = *reinterpret_cast<const half8*>(sact + pt1 * 128 + (k0 ^ s1));
#pragma unroll
        for (int ct = 0; ct < CT; ++ct) {
            acc[ct][0] = __builtin_amdgcn_mfma_f32_16x16x32_f16(wreg[ks & 1][ct], a0, acc[ct][0], 0, 0, 0);
            acc[ct][1] = __builtin_amdgcn_mfma_f32_16x16x32_f16(wreg[ks & 1][ct], a1, acc[ct][1], 0, 0, 0);
        }
    }
}

// same but B-operand fragments come from registers
template <int KS, int CT>
__device__ __forceinline__ void gemmRegB(floatx4 (&acc)[CT][2], const _Float16* __restrict__ wp,
                                         int cts, int ks0, int ct0,
                                         const half8 (&fr)[KS][2], int lane) {
    const _Float16* wbase = wp + ((size_t)(ks0 * cts + ct0) << 9) + lane * 8;
    half8 wreg[2][CT];
#pragma unroll
    for (int ct = 0; ct < CT; ++ct)
        wreg[0][ct] = *reinterpret_cast<const half8*>(wbase + ((size_t)ct << 9));
#pragma unroll
    for (int ks = 0; ks < KS; ++ks) {
        if (ks + 1 < KS) {
            const _Float16* wk = wbase + ((size_t)((ks + 1) * cts) << 9);
#pragma unroll
            for (int ct = 0; ct < CT; ++ct)
                wreg[(ks + 1) & 1][ct] = *reinterpret_cast<const half8*>(wk + ((size_t)ct << 9));
        }
#pragma unroll
        for (int ct = 0; ct < CT; ++ct) {
            acc[ct][0] = __builtin_amdgcn_mfma_f32_16x16x32_f16(wreg[ks & 1][ct], fr[ks][0], acc[ct][0], 0, 0, 0);
            acc[ct][1] = __builtin_amdgcn_mfma_f32_16x16x32_f16(wreg[ks & 1][ct], fr[ks][1], acc[ct][1], 0, 0, 0);
        }
    }
}

__device__ __forceinline__ void loadFrags(half8 (&fr)[4][2], const _Float16* sact, int ptb, int lane) {
    const int m = lane & 15, g = lane >> 4;
    const int pt0 = ptb + m, pt1 = pt0 + 16;
    const int s0 = swz(pt0), s1 = swz(pt1);
#pragma unroll
    for (int ks = 0; ks < 4; ++ks) {
        const int k0 = ks * 32 + g * 8;
        fr[ks][0] = *reinterpret_cast<const half8*>(sact + pt0 * 128 + (k0 ^ s0));
        fr[ks][1] = *reinterpret_cast<const half8*>(sact + pt1 * 128 + (k0 ^ s1));
    }
}

__device__ __forceinline__ void storeH4(_Float16* dst, int pt, int ch0,
                                        float o0, float o1, float o2, float o3) {
    half4v hv;
    hv[0] = (_Float16)o0; hv[1] = (_Float16)o1; hv[2] = (_Float16)o2; hv[3] = (_Float16)o3;
    *reinterpret_cast<half4v*>(dst + pt * 128 + (ch0 ^ swz(pt))) = hv;
}
__device__ __forceinline__ half4v loadH4(const _Float16* src, int pt, int ch0) {
    return *reinterpret_cast<const half4v*>(src + pt * 128 + (ch0 ^ swz(pt)));
}

// ---------------- main kernel ----------------------------------------------
__global__ void __launch_bounds__(256, 2)
ifd_mfma(const float* __restrict__ feat_s8, const float* __restrict__ feat1_s8,
         const float* __restrict__ feat_s16, const float* __restrict__ ctx_s8,
         const float* __restrict__ coarse_flow,
         const float* __restrict__ ctx_b, const float* __restrict__ gate1,
         const float* __restrict__ ffn1_b1, const float* __restrict__ ffn1_b2,
         const float* __restrict__ s8_b, const float* __restrict__ gate2,
         const float* __restrict__ ffn2_b1, const float* __restrict__ ffn2_b2,
         const float* __restrict__ hw1, const float* __restrict__ hb1,
         const float* __restrict__ hb2, const float* __restrict__ hb3,
         const float* __restrict__ hw4, const float* __restrict__ hb4,
         const _Float16* __restrict__ wsp, float* __restrict__ out) {
    __shared__ __align__(16) _Float16 bufA[128 * 128];
    __shared__ __align__(16) _Float16 bufB[128 * 128];
    __shared__ float sScal[4 * 128];
    __shared__ float sCps[2 * 128];
    __shared__ int   sIdx[3 * 4 * 128];
    __shared__ float sWgt[3 * 2 * 128];

    const int t = threadIdx.x;
    const int lane = t & 63, wid = t >> 6;
    const int m = lane & 15, g = lane >> 4;
    const int ptb = wid * 32;
    const int b = blockIdx.x / 1536;
    const int qbase = blockIdx.x * PPB;
    const float CHI = 1.0f - 1e-6f;

    // ---------- coords + coarse-flow sample + warp (threads 0..127)
    if (t < 128) {
        const int p = t;
        const int rem = qbase + p - b * PTS_PER_IMG;
        const int gy = rem >> 9, gx = rem & 511;
        float cnx = fminf(fmaxf(2.0f * ((float)gx + 0.5f) / 512.0f - 1.0f, -CHI), CHI);
        float cny = fminf(fmaxf(2.0f * ((float)gy + 0.5f) / 384.0f - 1.0f, -CHI), CHI);

        auto mkc = [](float cn, float Sf, int Smax, int& i0, int& i1, float& w) {
            float x = fminf(fmaxf(((cn + 1.0f) * Sf - 1.0f) * 0.5f, 0.0f), Sf - 1.0f);
            float xf = floorf(x);
            w = x - xf;
            i0 = (int)xf;
            i1 = (i0 + 1 > Smax) ? Smax : i0 + 1;
        };
        auto storeSet = [&](int s, int x0, int x1, int y0, int y1, float wx, float wy) {
            sIdx[s * 512 + 0 * 128 + p] = x0; sIdx[s * 512 + 1 * 128 + p] = x1;
            sIdx[s * 512 + 2 * 128 + p] = y0; sIdx[s * 512 + 3 * 128 + p] = y1;
            sWgt[s * 256 + p] = wx; sWgt[s * 256 + 128 + p] = wy;
        };

        int x0, x1, y0, y1; float wx, wy;
        mkc(cnx, 64.0f, 63, x0, x1, wx);
        mkc(cny, 48.0f, 47, y0, y1, wy);
        storeSet(0, x0, x1, y0, y1, wx, wy);

        int X0, X1, Y0, Y1; float WX, WY;
        mkc(cnx, 32.0f, 31, X0, X1, WX);
        mkc(cny, 24.0f, 23, Y0, Y1, WY);
        storeSet(1, X0, X1, Y0, Y1, WX, WY);

        const float w00 = (1.0f - wx) * (1.0f - wy), w01 = wx * (1.0f - wy);
        const float w10 = (1.0f - wx) * wy, w11 = wx * wy;
        const int i00 = y0 * 64 + x0, i01 = y0 * 64 + x1, i10 = y1 * 64 + x0, i11 = y1 * 64 + x1;
        const float* cf = coarse_flow + (size_t)b * 6144;
        float c0 = (cf[i00] * w00 + cf[i01] * w01 + cf[i10] * w10 + cf[i11] * w11) * 8.0f;
        const float* cf1 = cf + 3072;
        float c1 = (cf1[i00] * w00 + cf1[i01] * w01 + cf1[i10] * w10 + cf1[i11] * w11) * 8.0f;
        sCps[p] = c0; sCps[128 + p] = c1;
        sScal[p] = cnx; sScal[128 + p] = cny;
        sScal[256 + p] = c0 / 512.0f; sScal[384 + p] = c1 / 384.0f;

        float wxn = fminf(fmaxf(cnx + 2.0f * c0 / 512.0f, -CHI), CHI);
        float wyn = fminf(fmaxf(cny + 2.0f * c1 / 384.0f, -CHI), CHI);
        int u0, u1, v0, v1; float uw, vw;
        mkc(wxn, 64.0f, 63, u0, u1, uw);
        mkc(wyn, 48.0f, 47, v0, v1, vw);
        storeSet(2, u0, u1, v0, v1, uw, vw);
    }
    __syncthreads();   // B1

    auto sampleMap = [&](const float* __restrict__ mapB, int C, int HW, int Wd, int set,
                         _Float16* dst) {
        const int pt = t & 127, hs = t >> 7;
        const int x0 = sIdx[set * 512 + pt], x1 = sIdx[set * 512 + 128 + pt];
        const int y0 = sIdx[set * 512 + 256 + pt], y1 = sIdx[set * 512 + 384 + pt];
        const float wx = sWgt[set * 256 + pt], wy = sWgt[set * 256 + 128 + pt];
        const float w00 = (1.0f - wx) * (1.0f - wy), w01 = wx * (1.0f - wy);
        const float w10 = (1.0f - wx) * wy, w11 = wx * wy;
        const int i00 = y0 * Wd + x0, i01 = y0 * Wd + x1, i10 = y1 * Wd + x0, i11 = y1 * Wd + x1;
        const int np = C >> 2;
#pragma unroll 4
        for (int i = 0; i < np; ++i) {
            const int c0 = hs * (C >> 1) + 2 * i;
            const float* p0 = mapB + (size_t)c0 * HW;
            const float* p1 = p0 + HW;
            float v0 = p0[i00] * w00 + p0[i01] * w01 + p0[i10] * w10 + p0[i11] * w11;
            float v1 = p1[i00] * w00 + p1[i01] * w01 + p1[i10] * w10 + p1[i11] * w11;
            half2v hv; hv[0] = (_Float16)v0; hv[1] = (_Float16)v1;
            *reinterpret_cast<half2v*>(dst + pt * 128 + (c0 ^ swz(pt))) = hv;
        }
    };

    // ---------- sample f8 -> bufA, fctx -> bufB[:,0:64]
    sampleMap(feat_s8 + (size_t)b * 128 * 3072, 128, 3072, 64, 0, bufA);
    sampleMap(ctx_s8 + (size_t)b * 64 * 3072, 64, 3072, 64, 0, bufB);
    __syncthreads();   // B2

    // ---------- ctx: h2 = f8 + sig(g1)*(fctx @ ctx_w + ctx_b)   (bufB -> bufA)
    {
        floatx4 acc[8][2];
#pragma unroll
        for (int c = 0; c < 8; ++c) { acc[c][0] = (floatx4)0.0f; acc[c][1] = (floatx4)0.0f; }
        gemmT<2, 8>(acc, wsp + WS_CTX, 8, 0, 0, bufB, ptb, lane);
#pragma unroll
        for (int ct = 0; ct < 8; ++ct) {
            const int ch0 = ct * 16 + g * 4;
            const float4 bb = *reinterpret_cast<const float4*>(ctx_b + ch0);
            const float4 gg = *reinterpret_cast<const float4*>(gate1 + ch0);
            const float g0 = sigmoidf_(gg.x), g1v = sigmoidf_(gg.y),
                        g2v = sigmoidf_(gg.z), g3 = sigmoidf_(gg.w);
#pragma unroll
            for (int pr = 0; pr < 2; ++pr) {
                const int pt = ptb + pr * 16 + m;
                half4v rv = loadH4(bufA, pt, ch0);
                floatx4 v = acc[ct][pr];
                storeH4(bufA, pt, ch0,
                        (float)rv[0] + g0 * (v[0] + bb.x), (float)rv[1] + g1v * (v[1] + bb.y),
                        (float)rv[2] + g2v * (v[2] + bb.z), (float)rv[3] + g3 * (v[3] + bb.w));
            }
        }
    }

    // ---------- ffn1: bufA -> bufA (gelu h0 -> bufB, gelu h1 -> bufA; h2 dead)
    {
        {   // au0: W1 cols 0..127
            floatx4 au[8][2];
#pragma unroll
            for (int c = 0; c < 8; ++c) { au[c][0] = (floatx4)0.0f; au[c][1] = (floatx4)0.0f; }
            gemmT<4, 8>(au, wsp + WS_F1W1, 16, 0, 0, bufA, ptb, lane);
#pragma unroll
            for (int ct = 0; ct < 8; ++ct) {
                const int ch0 = ct * 16 + g * 4;
                const float4 bb = *reinterpret_cast<const float4*>(ffn1_b1 + ch0);
#pragma unroll
                for (int pr = 0; pr < 2; ++pr) {
                    const int pt = ptb + pr * 16 + m;
                    floatx4 v = au[ct][pr];
                    storeH4(bufB, pt, ch0, geluf_(v[0] + bb.x), geluf_(v[1] + bb.y),
                            geluf_(v[2] + bb.z), geluf_(v[3] + bb.w));
                }
            }
        }
        {   // au1: W1 cols 128..255 -> overwrite bufA (h2 dead; wave-private rows)
            floatx4 au[8][2];
#pragma unroll
            for (int c = 0; c < 8; ++c) { au[c][0] = (floatx4)0.0f; au[c][1] = (floatx4)0.0f; }
            gemmT<4, 8>(au, wsp + WS_F1W1, 16, 0, 8, bufA, ptb, lane);
#pragma unroll
            for (int ct = 0; ct < 8; ++ct) {
                const int ch0 = ct * 16 + g * 4;
                const float4 bb = *reinterpret_cast<const float4*>(ffn1_b1 + 128 + ch0);
#pragma unroll
                for (int pr = 0; pr < 2; ++pr) {
                    const int pt = ptb + pr * 16 + m;
                    floatx4 v = au[ct][pr];
                    storeH4(bufA, pt, ch0, geluf_(v[0] + bb.x), geluf_(v[1] + bb.y),
                            geluf_(v[2] + bb.z), geluf_(v[3] + bb.w));
                }
            }
        }
        {   // acc: W2 over bufB (k-tiles 0..3) + bufA (k-tiles 4..7) -> bufA
            floatx4 acc[8][2];
#pragma unroll
            for (int c = 0; c < 8; ++c) { acc[c][0] = (floatx4)0.0f; acc[c][1] = (floatx4)0.0f; }
            gemmT<4, 8>(acc, wsp + WS_F1W2, 8, 0, 0, bufB, ptb, lane);
            gemmT<4, 8>(acc, wsp + WS_F1W2, 8, 4, 0, bufA, ptb, lane);
#pragma unroll
            for (int ct = 0; ct < 8; ++ct) {
                const int ch0 = ct * 16 + g * 4;
                const float4 bb = *reinterpret_cast<const float4*>(ffn1_b2 + ch0);
#pragma unroll
                for (int pr = 0; pr < 2; ++pr) {
                    const int pt = ptb + pr * 16 + m;
                    floatx4 v = acc[ct][pr];
                    storeH4(bufA, pt, ch0, v[0] + bb.x, v[1] + bb.y, v[2] + bb.z, v[3] + bb.w);
                }
            }
        }
    }
    __syncthreads();   // B3

    // ---------- sample f16 -> bufB
    sampleMap(feat_s16 + (size_t)b * 128 * 768, 128, 768, 32, 1, bufB);
    __syncthreads();   // B4

    // ---------- s8: h3 = f16 + sig(g2)*(h2' @ s8_w + s8_b)   (bufA -> bufB)
    {
        floatx4 acc[8][2];
#pragma unroll
        for (int c = 0; c < 8; ++c) { acc[c][0] = (floatx4)0.0f; acc[c][1] = (floatx4)0.0f; }
        gemmT<4, 8>(acc, wsp + WS_S8, 8, 0, 0, bufA, ptb, lane);
#pragma unroll
        for (int ct = 0; ct < 8; ++ct) {
            const int ch0 = ct * 16 + g * 4;
            const float4 bb = *reinterpret_cast<const float4*>(s8_b + ch0);
            const float4 gg = *reinterpret_cast<const float4*>(gate2 + ch0);
            const float g0 = sigmoidf_(gg.x), g1v = sigmoidf_(gg.y),
                        g2v = sigmoidf_(gg.z), g3 = sigmoidf_(gg.w);
#pragma unroll
            for (int pr = 0; pr < 2; ++pr) {
                const int pt = ptb + pr * 16 + m;
                half4v rv = loadH4(bufB, pt, ch0);
                floatx4 v = acc[ct][pr];
                storeH4(bufB, pt, ch0,
                        (float)rv[0] + g0 * (v[0] + bb.x), (float)rv[1] + g1v * (v[1] + bb.y),
                        (float)rv[2] + g2v * (v[2] + bb.z), (float)rv[3] + g3 * (v[3] + bb.w));
            }
        }
    }

    // ---------- ffn2: bufB -> bufB (gelu h0 -> bufA, gelu h1 -> bufB; h3 dead)
    {
        {   // au0
            floatx4 au[8][2];
#pragma unroll
            for (int c = 0; c < 8; ++c) { au[c][0] = (floatx4)0.0f; au[c][1] = (floatx4)0.0f; }
            gemmT<4, 8>(au, wsp + WS_F2W1, 16, 0, 0, bufB, ptb, lane);
#pragma unroll
            for (int ct = 0; ct < 8; ++ct) {
                const int ch0 = ct * 16 + g * 4;
                const float4 bb = *reinterpret_cast<const float4*>(ffn2_b1 + ch0);
#pragma unroll
                for (int pr = 0; pr < 2; ++pr) {
                    const int pt = ptb + pr * 16 + m;
                    floatx4 v = au[ct][pr];
                    storeH4(bufA, pt, ch0, geluf_(v[0] + bb.x), geluf_(v[1] + bb.y),
                            geluf_(v[2] + bb.z), geluf_(v[3] + bb.w));
                }
            }
        }
        {   // au1 -> overwrite bufB (h3 dead; wave-private rows)
            floatx4 au[8][2];
#pragma unroll
            for (int c = 0; c < 8; ++c) { au[c][0] = (floatx4)0.0f; au[c][1] = (floatx4)0.0f; }
            gemmT<4, 8>(au, wsp + WS_F2W1, 16, 0, 8, bufB, ptb, lane);
#pragma unroll
            for (int ct = 0; ct < 8; ++ct) {
                const int ch0 = ct * 16 + g * 4;
                const float4 bb = *reinterpret_cast<const float4*>(ffn2_b1 + 128 + ch0);
#pragma unroll
                for (int pr = 0; pr < 2; ++pr) {
                    const int pt = ptb + pr * 16 + m;
                    floatx4 v = au[ct][pr];
                    storeH4(bufB, pt, ch0, geluf_(v[0] + bb.x), geluf_(v[1] + bb.y),
                            geluf_(v[2] + bb.z), geluf_(v[3] + bb.w));
                }
            }
        }
        {   // acc: W2 over bufA (k 0..3) + bufB (k 4..7) -> bufB (fused)
            floatx4 acc[8][2];
#pragma unroll
            for (int c = 0; c < 8; ++c) { acc[c][0] = (floatx4)0.0f; acc[c][1] = (floatx4)0.0f; }
            gemmT<4, 8>(acc, wsp + WS_F2W2, 8, 0, 0, bufA, ptb, lane);
            gemmT<4, 8>(acc, wsp + WS_F2W2, 8, 4, 0, bufB, ptb, lane);
#pragma unroll
            for (int ct = 0; ct < 8; ++ct) {
                const int ch0 = ct * 16 + g * 4;
                const float4 bb = *reinterpret_cast<const float4*>(ffn2_b2 + ch0);
#pragma unroll
                for (int pr = 0; pr < 2; ++pr) {
                    const int pt = ptb + pr * 16 + m;
                    floatx4 v = acc[ct][pr];
                    storeH4(bufB, pt, ch0, v[0] + bb.x, v[1] + bb.y, v[2] + bb.z, v[3] + bb.w);
                }
            }
        }
    }
    __syncthreads();   // B5

    // ---------- sample f1w -> bufA
    sampleMap(feat1_s8 + (size_t)b * 128 * 3072, 128, 3072, 64, 2, bufA);
    __syncthreads();   // B6

    // ---------- head1 (260->256 relu), two 8-tile halves; f1w in register frags
    {
        half8 fw[4][2];
        loadFrags(fw, bufA, ptb, lane);   // wave-private rows; frees bufA for output
#pragma unroll
        for (int hf = 0; hf < 2; ++hf) {
            floatx4 acc[8][2];
#pragma unroll
            for (int c = 0; c < 8; ++c) { acc[c][0] = (floatx4)0.0f; acc[c][1] = (floatx4)0.0f; }
            gemmT<4, 8>(acc, wsp + WS_HW1, 16, 0, hf * 8, bufB, ptb, lane);      // fused rows 0..127
            gemmRegB<4, 8>(acc, wsp + WS_HW1, 16, 4, hf * 8, fw, lane);          // f1w rows 128..255
#pragma unroll
            for (int ct = 0; ct < 8; ++ct) {
                const int ch0 = ct * 16 + g * 4;
#pragma unroll
                for (int jj = 0; jj < 4; ++jj) {                                  // scal rows 256..259
                    const float4 wj = *reinterpret_cast<const float4*>(
                        hw1 + (size_t)(256 + jj) * 256 + hf * 128 + ch0);
#pragma unroll
                    for (int pr = 0; pr < 2; ++pr) {
                        const int pt = ptb + pr * 16 + m;
                        const float s = sScal[jj * 128 + pt];
                        floatx4 v = acc[ct][pr];
                        v[0] = fmaf(wj.x, s, v[0]); v[1] = fmaf(wj.y, s, v[1]);
                        v[2] = fmaf(wj.z, s, v[2]); v[3] = fmaf(wj.w, s, v[3]);
                        acc[ct][pr] = v;
                    }
                }
                const float4 bb = *reinterpret_cast<const float4*>(hb1 + hf * 128 + ch0);
                _Float16* dst = hf ? bufB : bufA;
#pragma unroll
                for (int pr = 0; pr < 2; ++pr) {
                    const int pt = ptb + pr * 16 + m;
                    floatx4 v = acc[ct][pr];
                    storeH4(dst, pt, ch0, fmaxf(v[0] + bb.x, 0.0f), fmaxf(v[1] + bb.y, 0.0f),
                            fmaxf(v[2] + bb.z, 0.0f), fmaxf(v[3] + bb.w, 0.0f));
                }
            }
        }
    }

    // ---------- head2 (256->128 relu): a1 lo=bufA, hi=bufB -> bufA
    {
        floatx4 acc[8][2];
#pragma unroll
        for (int c = 0; c < 8; ++c) { acc[c][0] = (floatx4)0.0f; acc[c][1] = (floatx4)0.0f; }
        gemmT<4, 8>(acc, wsp + WS_HW2, 8, 0, 0, bufA, ptb, lane);
        gemmT<4, 8>(acc, wsp + WS_HW2, 8, 4, 0, bufB, ptb, lane);
#pragma unroll
        for (int ct = 0; ct < 8; ++ct) {
            const int ch0 = ct * 16 + g * 4;
            const float4 bb = *reinterpret_cast<const float4*>(hb2 + ch0);
#pragma unroll
            for (int pr = 0; pr < 2; ++pr) {
                const int pt = ptb + pr * 16 + m;
                floatx4 v = acc[ct][pr];
                storeH4(bufA, pt, ch0, fmaxf(v[0] + bb.x, 0.0f), fmaxf(v[1] + bb.y, 0.0f),
                        fmaxf(v[2] + bb.z, 0.0f), fmaxf(v[3] + bb.w, 0.0f));
            }
        }
    }

    // ---------- head3 (128->64 relu): bufA -> bufB[:,0:64]
    {
        floatx4 acc[4][2];
#pragma unroll
        for (int c = 0; c < 4; ++c) { acc[c][0] = (floatx4)0.0f; acc[c][1] = (floatx4)0.0f; }
        gemmT<4, 4>(acc, wsp + WS_HW3, 4, 0, 0, bufA, ptb, lane);
#pragma unroll
        for (int ct = 0; ct < 4; ++ct) {
            const int ch0 = ct * 16 + g * 4;
            const float4 bb = *reinterpret_cast<const float4*>(hb3 + ch0);
#pragma unroll
            for (int pr = 0; pr < 2; ++pr) {
                const int pt = ptb + pr * 16 + m;
                floatx4 v = acc[ct][pr];
                storeH4(bufB, pt, ch0, fmaxf(v[0] + bb.x, 0.0f), fmaxf(v[1] + bb.y, 0.0f),
                        fmaxf(v[2] + bb.z, 0.0f), fmaxf(v[3] + bb.w, 0.0f));
            }
        }
    }
    __syncthreads();   // B7

    // ---------- head4 (64->2) fp32 + flow combine + store
    {
        const int pp = t >> 1, j = t & 1;
        float d = hb4[j];
#pragma unroll
        for (int i8 = 0; i8 < 8; ++i8) {
            const int c0 = i8 * 8;
            half8 hv = *reinterpret_cast<const half8*>(bufB + pp * 128 + (c0 ^ swz(pp)));
#pragma unroll
            for (int j2 = 0; j2 < 8; ++j2)
                d = fmaf((float)hv[j2], hw4[(c0 + j2) * 2 + j], d);
        }
        const int q = qbase + pp;
        const int rem = q - b * PTS_PER_IMG;
        const int gy = rem >> 9, gx = rem & 511;
        const float flow = sCps[j * 128 + pp] + d * (j == 0 ? 512.0f : 384.0f);
        out[(((size_t)b * 2 + j) * 384 + gy) * 512 + gx] = flow;
    }
}

extern "C" void kernel_launch(void* const* d_in, const int* in_sizes, int n_in,
                              void* d_out, int out_size, void* d_ws, size_t ws_size,
                              hipStream_t stream) {
    const float* feat_s8 = (const float*)d_in[1];
    const float* feat1_s8 = (const float*)d_in[2];
    const float* feat_s16 = (const float*)d_in[3];
    const float* ctx_s8 = (const float*)d_in[4];
    const float* coarse_flow = (const float*)d_in[5];
    const float* ctx_w = (const float*)d_in[6];
    const float* ctx_b = (const float*)d_in[7];
    const float* gate1 = (const float*)d_in[8];
    const float* ffn1_w1 = (const float*)d_in[9];
    const float* ffn1_b1 = (const float*)d_in[10];
    const float* ffn1_w2 = (const float*)d_in[11];
    const float* ffn1_b2 = (const float*)d_in[12];
    const float* s8_w = (const float*)d_in[13];
    const float* s8_b = (const float*)d_in[14];
    const float* gate2 = (const float*)d_in[15];
    const float* ffn2_w1 = (const float*)d_in[16];
    const float* ffn2_b1 = (const float*)d_in[17];
    const float* ffn2_w2 = (const float*)d_in[18];
    const float* ffn2_b2 = (const float*)d_in[19];
    const float* hw1 = (const float*)d_in[20];
    const float* hb1 = (const float*)d_in[21];
    const float* hw2 = (const float*)d_in[22];
    const float* hb2 = (const float*)d_in[23];
    const float* hw3 = (const float*)d_in[24];
    const float* hb3 = (const float*)d_in[25];
    const float* hw4 = (const float*)d_in[26];
    const float* hb4 = (const float*)d_in[27];
    float* out = (float*)d_out;
    _Float16* wsp = (_Float16*)d_ws;

    prepack_kernel<<<dim3(512), dim3(64), 0, stream>>>(
        ctx_w, ffn1_w1, ffn1_w2, s8_w, ffn2_w1, ffn2_w2, hw1, hw2, hw3, wsp);

    ifd_mfma<<<dim3(NBLOCKS), dim3(256), 0, stream>>>(
        feat_s8, feat1_s8, feat_s16, ctx_s8, coarse_flow,
        ctx_b, gate1, ffn1_b1, ffn1_b2, s8_b, gate2, ffn2_b1, ffn2_b2,
        hw1, hb1, hb2, hb3, hw4, hb4, wsp, out);
}

// Round 6
// 806.048 us; speedup vs baseline: 1.2556x; 1.2556x over previous
//
#include <hip/hip_runtime.h>
#include <math.h>

// ImplicitFlowDecoder round 6: f16 MFMA megakernel, 8 waves/block.
// Round-6 changes vs round 5:
//   * REVERT r5 weight-register-prefetch (blew the 128-VGPR allocator target ->
//     spilled: WRITE_SIZE 81.8MB, dur regressed 793->1012).
//   * 512 threads/block (8 waves x 16 pts). LDS unchanged (76.8KB, 2 blocks/CU)
//     -> 16 waves/CU = 4 waves/SIMD (was 2): 2x latency hiding for L2 weight
//     stream; accumulators halve (acc[8] floatx4) freeing regs for load hoisting.

typedef _Float16 half8 __attribute__((ext_vector_type(8)));
typedef _Float16 half4v __attribute__((ext_vector_type(4)));
typedef _Float16 half2v __attribute__((ext_vector_type(2)));
typedef float floatx4 __attribute__((ext_vector_type(4)));

#define NPOINTS_TOTAL (2 * 384 * 512)
#define PPB 128
#define NBLOCKS (NPOINTS_TOTAL / PPB)
#define PTS_PER_IMG 196608

#define WS_CTX   0
#define WS_F1W1  8192
#define WS_F1W2  40960
#define WS_S8    73728
#define WS_F2W1  90112
#define WS_F2W2  122880
#define WS_HW1   155648
#define WS_HW2   221184
#define WS_HW3   253952

__device__ __forceinline__ float sigmoidf_(float x) { return 1.0f / (1.0f + expf(-x)); }
// exact-form gelu via A-S 7.1.26 erf approximation (abs err <= 1.5e-7)
__device__ __forceinline__ float geluf_(float x) {
    const float ax = fabsf(x) * 0.70710678118654752f;
    const float t = 1.0f / fmaf(0.3275911f, ax, 1.0f);
    float poly = fmaf(t, 1.061405429f, -1.453152027f);
    poly = fmaf(t, poly, 1.421413741f);
    poly = fmaf(t, poly, -0.284496736f);
    poly = fmaf(t, poly, 0.254829592f);
    poly *= t;
    float er = 1.0f - poly * expf(-ax * ax);
    er = copysignf(er, x);
    return 0.5f * x * (1.0f + er);
}
__device__ __forceinline__ int swz(int pt) { return (pt & 15) << 3; }

// ---------------- prepack: W[K][N] fp32 -> f16 fragments -------------------
__global__ void prepack_kernel(const float* __restrict__ ctx_w, const float* __restrict__ f1w1,
                               const float* __restrict__ f1w2, const float* __restrict__ s8w,
                               const float* __restrict__ f2w1, const float* __restrict__ f2w2,
                               const float* __restrict__ hw1, const float* __restrict__ hw2,
                               const float* __restrict__ hw3, _Float16* __restrict__ ws) {
    const int bid = blockIdx.x;
    const int lane = threadIdx.x;
    const float* src; int N, CT, start; size_t ofsH;
    if (bid < 16)       { src = ctx_w; N = 128; CT = 8;  start = 0;   ofsH = WS_CTX; }
    else if (bid < 80)  { src = f1w1;  N = 256; CT = 16; start = 16;  ofsH = WS_F1W1; }
    else if (bid < 144) { src = f1w2;  N = 128; CT = 8;  start = 80;  ofsH = WS_F1W2; }
    else if (bid < 176) { src = s8w;   N = 128; CT = 8;  start = 144; ofsH = WS_S8; }
    else if (bid < 240) { src = f2w1;  N = 256; CT = 16; start = 176; ofsH = WS_F2W1; }
    else if (bid < 304) { src = f2w2;  N = 128; CT = 8;  start = 240; ofsH = WS_F2W2; }
    else if (bid < 432) { src = hw1;   N = 256; CT = 16; start = 304; ofsH = WS_HW1; }
    else if (bid < 496) { src = hw2;   N = 128; CT = 8;  start = 432; ofsH = WS_HW2; }
    else                { src = hw3;   N = 64;  CT = 4;  start = 496; ofsH = WS_HW3; }
    const int ti = bid - start;
    const int ks = ti / CT, ct = ti % CT;
    const int m = lane & 15, g = lane >> 4;
    const int kb = ks * 32 + g * 8;
    const int n = ct * 16 + m;
    half8 v;
#pragma unroll
    for (int j = 0; j < 8; ++j) v[j] = (_Float16)src[(size_t)(kb + j) * N + n];
    *reinterpret_cast<half8*>(ws + ofsH + (size_t)ti * 512 + lane * 8) = v;
}

// ---------------- GEMM cores (16 pts/wave: single point-rep) ---------------
template <int KS, int CT>
__device__ __forceinline__ void gemmT(floatx4 (&acc)[CT], const _Float16* __restrict__ wp,
                                      int cts, int ks0, int ct0,
                                      const _Float16* sact, int ptb, int lane) {
    const int m = lane & 15, g = lane >> 4;
    const int pt0 = ptb + m;
    const int s0 = swz(pt0);
    const _Float16* wbase = wp + ((size_t)(ks0 * cts + ct0) << 9) + lane * 8;
#pragma unroll
    for (int ks = 0; ks < KS; ++ks) {
        const int k0 = ks * 32 + g * 8;
        half8 a0 = *reinterpret_cast<const half8*>(sact + pt0 * 128 + (k0 ^ s0));
        const _Float16* wk = wbase + ((size_t)(ks * cts) << 9);
#pragma unroll
        for (int ct = 0; ct < CT; ++ct) {
            half8 w = *reinterpret_cast<const half8*>(wk + ((size_t)ct << 9));
            acc[ct] = __builtin_amdgcn_mfma_f32_16x16x32_f16(w, a0, acc[ct], 0, 0, 0);
        }
    }
}

// same but B-operand fragments come from registers
template <int KS, int CT>
__device__ __forceinline__ void gemmRegB(floatx4 (&acc)[CT], const _Float16* __restrict__ wp,
                                         int cts, int ks0, int ct0,
                                         const half8 (&fr)[KS], int lane) {
    const _Float16* wbase = wp + ((size_t)(ks0 * cts + ct0) << 9) + lane * 8;
#pragma unroll
    for (int ks = 0; ks < KS; ++ks) {
        const _Float16* wk = wbase + ((size_t)(ks * cts) << 9);
#pragma unroll
        for (int ct = 0; ct < CT; ++ct) {
            half8 w = *reinterpret_cast<const half8*>(wk + ((size_t)ct << 9));
            acc[ct] = __builtin_amdgcn_mfma_f32_16x16x32_f16(w, fr[ks], acc[ct], 0, 0, 0);
        }
    }
}

__device__ __forceinline__ void loadFrags(half8 (&fr)[4], const _Float16* sact, int ptb, int lane) {
    const int m = lane & 15, g = lane >> 4;
    const int pt0 = ptb + m;
    const int s0 = swz(pt0);
#pragma unroll
    for (int ks = 0; ks < 4; ++ks) {
        const int k0 = ks * 32 + g * 8;
        fr[ks] = *reinterpret_cast<const half8*>(sact + pt0 * 128 + (k0 ^ s0));
    }
}

__device__ __forceinline__ void storeH4(_Float16* dst, int pt, int ch0,
                                        float o0, float o1, float o2, float o3) {
    half4v hv;
    hv[0] = (_Float16)o0; hv[1] = (_Float16)o1; hv[2] = (_Float16)o2; hv[3] = (_Float16)o3;
    *reinterpret_cast<half4v*>(dst + pt * 128 + (ch0 ^ swz(pt))) = hv;
}
__device__ __forceinline__ half4v loadH4(const _Float16* src, int pt, int ch0) {
    return *reinterpret_cast<const half4v*>(src + pt * 128 + (ch0 ^ swz(pt)));
}

// ---------------- main kernel ----------------------------------------------
__global__ void __launch_bounds__(512, 4)
ifd_mfma(const float* __restrict__ feat_s8, const float* __restrict__ feat1_s8,
         const float* __restrict__ feat_s16, const float* __restrict__ ctx_s8,
         const float* __restrict__ coarse_flow,
         const float* __restrict__ ctx_b, const float* __restrict__ gate1,
         const float* __restrict__ ffn1_b1, const float* __restrict__ ffn1_b2,
         const float* __restrict__ s8_b, const float* __restrict__ gate2,
         const float* __restrict__ ffn2_b1, const float* __restrict__ ffn2_b2,
         const float* __restrict__ hw1, const float* __restrict__ hb1,
         const float* __restrict__ hb2, const float* __restrict__ hb3,
         const float* __restrict__ hw4, const float* __restrict__ hb4,
         const _Float16* __restrict__ wsp, float* __restrict__ out) {
    __shared__ __align__(16) _Float16 bufA[128 * 128];
    __shared__ __align__(16) _Float16 bufB[128 * 128];
    __shared__ float sScal[4 * 128];
    __shared__ float sCps[2 * 128];
    __shared__ int   sIdx[3 * 4 * 128];
    __shared__ float sWgt[3 * 2 * 128];

    const int t = threadIdx.x;
    const int lane = t & 63, wid = t >> 6;            // 8 waves
    const int m = lane & 15, g = lane >> 4;
    const int ptb = wid * 16;                          // 16 pts per wave
    const int b = blockIdx.x / 1536;
    const int qbase = blockIdx.x * PPB;
    const float CHI = 1.0f - 1e-6f;

    // ---------- coords + coarse-flow sample + warp (threads 0..127)
    if (t < 128) {
        const int p = t;
        const int rem = qbase + p - b * PTS_PER_IMG;
        const int gy = rem >> 9, gx = rem & 511;
        float cnx = fminf(fmaxf(2.0f * ((float)gx + 0.5f) / 512.0f - 1.0f, -CHI), CHI);
        float cny = fminf(fmaxf(2.0f * ((float)gy + 0.5f) / 384.0f - 1.0f, -CHI), CHI);

        auto mkc = [](float cn, float Sf, int Smax, int& i0, int& i1, float& w) {
            float x = fminf(fmaxf(((cn + 1.0f) * Sf - 1.0f) * 0.5f, 0.0f), Sf - 1.0f);
            float xf = floorf(x);
            w = x - xf;
            i0 = (int)xf;
            i1 = (i0 + 1 > Smax) ? Smax : i0 + 1;
        };
        auto storeSet = [&](int s, int x0, int x1, int y0, int y1, float wx, float wy) {
            sIdx[s * 512 + 0 * 128 + p] = x0; sIdx[s * 512 + 1 * 128 + p] = x1;
            sIdx[s * 512 + 2 * 128 + p] = y0; sIdx[s * 512 + 3 * 128 + p] = y1;
            sWgt[s * 256 + p] = wx; sWgt[s * 256 + 128 + p] = wy;
        };

        int x0, x1, y0, y1; float wx, wy;
        mkc(cnx, 64.0f, 63, x0, x1, wx);
        mkc(cny, 48.0f, 47, y0, y1, wy);
        storeSet(0, x0, x1, y0, y1, wx, wy);

        int X0, X1, Y0, Y1; float WX, WY;
        mkc(cnx, 32.0f, 31, X0, X1, WX);
        mkc(cny, 24.0f, 23, Y0, Y1, WY);
        storeSet(1, X0, X1, Y0, Y1, WX, WY);

        const float w00 = (1.0f - wx) * (1.0f - wy), w01 = wx * (1.0f - wy);
        const float w10 = (1.0f - wx) * wy, w11 = wx * wy;
        const int i00 = y0 * 64 + x0, i01 = y0 * 64 + x1, i10 = y1 * 64 + x0, i11 = y1 * 64 + x1;
        const float* cf = coarse_flow + (size_t)b * 6144;
        float c0 = (cf[i00] * w00 + cf[i01] * w01 + cf[i10] * w10 + cf[i11] * w11) * 8.0f;
        const float* cf1 = cf + 3072;
        float c1 = (cf1[i00] * w00 + cf1[i01] * w01 + cf1[i10] * w10 + cf1[i11] * w11) * 8.0f;
        sCps[p] = c0; sCps[128 + p] = c1;
        sScal[p] = cnx; sScal[128 + p] = cny;
        sScal[256 + p] = c0 / 512.0f; sScal[384 + p] = c1 / 384.0f;

        float wxn = fminf(fmaxf(cnx + 2.0f * c0 / 512.0f, -CHI), CHI);
        float wyn = fminf(fmaxf(cny + 2.0f * c1 / 384.0f, -CHI), CHI);
        int u0, u1, v0, v1; float uw, vw;
        mkc(wxn, 64.0f, 63, u0, u1, uw);
        mkc(wyn, 48.0f, 47, v0, v1, vw);
        storeSet(2, u0, u1, v0, v1, uw, vw);
    }
    __syncthreads();   // B1

    // thread t samples point (t&127), channel-quarter (t>>7): C/4 channels each
    auto sampleMap = [&](const float* __restrict__ mapB, int C, int HW, int Wd, int set,
                         _Float16* dst) {
        const int pt = t & 127, hs = t >> 7;           // hs in 0..3
        const int x0 = sIdx[set * 512 + pt], x1 = sIdx[set * 512 + 128 + pt];
        const int y0 = sIdx[set * 512 + 256 + pt], y1 = sIdx[set * 512 + 384 + pt];
        const float wx = sWgt[set * 256 + pt], wy = sWgt[set * 256 + 128 + pt];
        const float w00 = (1.0f - wx) * (1.0f - wy), w01 = wx * (1.0f - wy);
        const float w10 = (1.0f - wx) * wy, w11 = wx * wy;
        const int i00 = y0 * Wd + x0, i01 = y0 * Wd + x1, i10 = y1 * Wd + x0, i11 = y1 * Wd + x1;
        const int np = C >> 3;                          // channel-pairs per thread
#pragma unroll 4
        for (int i = 0; i < np; ++i) {
            const int c0 = hs * (C >> 2) + 2 * i;
            const float* p0 = mapB + (size_t)c0 * HW;
            const float* p1 = p0 + HW;
            float v0 = p0[i00] * w00 + p0[i01] * w01 + p0[i10] * w10 + p0[i11] * w11;
            float v1 = p1[i00] * w00 + p1[i01] * w01 + p1[i10] * w10 + p1[i11] * w11;
            half2v hv; hv[0] = (_Float16)v0; hv[1] = (_Float16)v1;
            *reinterpret_cast<half2v*>(dst + pt * 128 + (c0 ^ swz(pt))) = hv;
        }
    };

    // ---------- sample f8 -> bufA, fctx -> bufB[:,0:64]
    sampleMap(feat_s8 + (size_t)b * 128 * 3072, 128, 3072, 64, 0, bufA);
    sampleMap(ctx_s8 + (size_t)b * 64 * 3072, 64, 3072, 64, 0, bufB);
    __syncthreads();   // B2

    // ---------- ctx: h2 = f8 + sig(g1)*(fctx @ ctx_w + ctx_b)   (bufB -> bufA)
    {
        floatx4 acc[8];
#pragma unroll
        for (int c = 0; c < 8; ++c) acc[c] = (floatx4)0.0f;
        gemmT<2, 8>(acc, wsp + WS_CTX, 8, 0, 0, bufB, ptb, lane);
        const int pt = ptb + m;
#pragma unroll
        for (int ct = 0; ct < 8; ++ct) {
            const int ch0 = ct * 16 + g * 4;
            const float4 bb = *reinterpret_cast<const float4*>(ctx_b + ch0);
            const float4 gg = *reinterpret_cast<const float4*>(gate1 + ch0);
            const float g0 = sigmoidf_(gg.x), g1v = sigmoidf_(gg.y),
                        g2v = sigmoidf_(gg.z), g3 = sigmoidf_(gg.w);
            half4v rv = loadH4(bufA, pt, ch0);
            floatx4 v = acc[ct];
            storeH4(bufA, pt, ch0,
                    (float)rv[0] + g0 * (v[0] + bb.x), (float)rv[1] + g1v * (v[1] + bb.y),
                    (float)rv[2] + g2v * (v[2] + bb.z), (float)rv[3] + g3 * (v[3] + bb.w));
        }
    }

    // ---------- ffn1: bufA -> bufA (gelu h0 -> bufB, gelu h1 -> bufA; h2 dead)
    {
        const int pt = ptb + m;
        {   // au0: W1 cols 0..127
            floatx4 au[8];
#pragma unroll
            for (int c = 0; c < 8; ++c) au[c] = (floatx4)0.0f;
            gemmT<4, 8>(au, wsp + WS_F1W1, 16, 0, 0, bufA, ptb, lane);
#pragma unroll
            for (int ct = 0; ct < 8; ++ct) {
                const int ch0 = ct * 16 + g * 4;
                const float4 bb = *reinterpret_cast<const float4*>(ffn1_b1 + ch0);
                floatx4 v = au[ct];
                storeH4(bufB, pt, ch0, geluf_(v[0] + bb.x), geluf_(v[1] + bb.y),
                        geluf_(v[2] + bb.z), geluf_(v[3] + bb.w));
            }
        }
        {   // au1: W1 cols 128..255 -> overwrite bufA (h2 dead; wave-private rows)
            floatx4 au[8];
#pragma unroll
            for (int c = 0; c < 8; ++c) au[c] = (floatx4)0.0f;
            gemmT<4, 8>(au, wsp + WS_F1W1, 16, 0, 8, bufA, ptb, lane);
#pragma unroll
            for (int ct = 0; ct < 8; ++ct) {
                const int ch0 = ct * 16 + g * 4;
                const float4 bb = *reinterpret_cast<const float4*>(ffn1_b1 + 128 + ch0);
                floatx4 v = au[ct];
                storeH4(bufA, pt, ch0, geluf_(v[0] + bb.x), geluf_(v[1] + bb.y),
                        geluf_(v[2] + bb.z), geluf_(v[3] + bb.w));
            }
        }
        {   // acc: W2 over bufB (k-tiles 0..3) + bufA (k-tiles 4..7) -> bufA
            floatx4 acc[8];
#pragma unroll
            for (int c = 0; c < 8; ++c) acc[c] = (floatx4)0.0f;
            gemmT<4, 8>(acc, wsp + WS_F1W2, 8, 0, 0, bufB, ptb, lane);
            gemmT<4, 8>(acc, wsp + WS_F1W2, 8, 4, 0, bufA, ptb, lane);
#pragma unroll
            for (int ct = 0; ct < 8; ++ct) {
                const int ch0 = ct * 16 + g * 4;
                const float4 bb = *reinterpret_cast<const float4*>(ffn1_b2 + ch0);
                floatx4 v = acc[ct];
                storeH4(bufA, pt, ch0, v[0] + bb.x, v[1] + bb.y, v[2] + bb.z, v[3] + bb.w);
            }
        }
    }
    __syncthreads();   // B3

    // ---------- sample f16 -> bufB
    sampleMap(feat_s16 + (size_t)b * 128 * 768, 128, 768, 32, 1, bufB);
    __syncthreads();   // B4

    // ---------- s8: h3 = f16 + sig(g2)*(h2' @ s8_w + s8_b)   (bufA -> bufB)
    {
        floatx4 acc[8];
#pragma unroll
        for (int c = 0; c < 8; ++c) acc[c] = (floatx4)0.0f;
        gemmT<4, 8>(acc, wsp + WS_S8, 8, 0, 0, bufA, ptb, lane);
        const int pt = ptb + m;
#pragma unroll
        for (int ct = 0; ct < 8; ++ct) {
            const int ch0 = ct * 16 + g * 4;
            const float4 bb = *reinterpret_cast<const float4*>(s8_b + ch0);
            const float4 gg = *reinterpret_cast<const float4*>(gate2 + ch0);
            const float g0 = sigmoidf_(gg.x), g1v = sigmoidf_(gg.y),
                        g2v = sigmoidf_(gg.z), g3 = sigmoidf_(gg.w);
            half4v rv = loadH4(bufB, pt, ch0);
            floatx4 v = acc[ct];
            storeH4(bufB, pt, ch0,
                    (float)rv[0] + g0 * (v[0] + bb.x), (float)rv[1] + g1v * (v[1] + bb.y),
                    (float)rv[2] + g2v * (v[2] + bb.z), (float)rv[3] + g3 * (v[3] + bb.w));
        }
    }

    // ---------- ffn2: bufB -> bufB (gelu h0 -> bufA, gelu h1 -> bufB; h3 dead)
    {
        const int pt = ptb + m;
        {   // au0
            floatx4 au[8];
#pragma unroll
            for (int c = 0; c < 8; ++c) au[c] = (floatx4)0.0f;
            gemmT<4, 8>(au, wsp + WS_F2W1, 16, 0, 0, bufB, ptb, lane);
#pragma unroll
            for (int ct = 0; ct < 8; ++ct) {
                const int ch0 = ct * 16 + g * 4;
                const float4 bb = *reinterpret_cast<const float4*>(ffn2_b1 + ch0);
                floatx4 v = au[ct];
                storeH4(bufA, pt, ch0, geluf_(v[0] + bb.x), geluf_(v[1] + bb.y),
                        geluf_(v[2] + bb.z), geluf_(v[3] + bb.w));
            }
        }
        {   // au1 -> overwrite bufB (h3 dead; wave-private rows)
            floatx4 au[8];
#pragma unroll
            for (int c = 0; c < 8; ++c) au[c] = (floatx4)0.0f;
            gemmT<4, 8>(au, wsp + WS_F2W1, 16, 0, 8, bufB, ptb, lane);
#pragma unroll
            for (int ct = 0; ct < 8; ++ct) {
                const int ch0 = ct * 16 + g * 4;
                const float4 bb = *reinterpret_cast<const float4*>(ffn2_b1 + 128 + ch0);
                floatx4 v = au[ct];
                storeH4(bufB, pt, ch0, geluf_(v[0] + bb.x), geluf_(v[1] + bb.y),
                        geluf_(v[2] + bb.z), geluf_(v[3] + bb.w));
            }
        }
        {   // acc: W2 over bufA (k 0..3) + bufB (k 4..7) -> bufB (fused)
            floatx4 acc[8];
#pragma unroll
            for (int c = 0; c < 8; ++c) acc[c] = (floatx4)0.0f;
            gemmT<4, 8>(acc, wsp + WS_F2W2, 8, 0, 0, bufA, ptb, lane);
            gemmT<4, 8>(acc, wsp + WS_F2W2, 8, 4, 0, bufB, ptb, lane);
#pragma unroll
            for (int ct = 0; ct < 8; ++ct) {
                const int ch0 = ct * 16 + g * 4;
                const float4 bb = *reinterpret_cast<const float4*>(ffn2_b2 + ch0);
                floatx4 v = acc[ct];
                storeH4(bufB, pt, ch0, v[0] + bb.x, v[1] + bb.y, v[2] + bb.z, v[3] + bb.w);
            }
        }
    }
    __syncthreads();   // B5

    // ---------- sample f1w -> bufA
    sampleMap(feat1_s8 + (size_t)b * 128 * 3072, 128, 3072, 64, 2, bufA);
    __syncthreads();   // B6

    // ---------- head1 (260->256 relu), two 8-tile halves; f1w in register frags
    {
        const int pt = ptb + m;
        half8 fw[4];
        loadFrags(fw, bufA, ptb, lane);   // wave-private rows; frees bufA for output
#pragma unroll
        for (int hf = 0; hf < 2; ++hf) {
            floatx4 acc[8];
#pragma unroll
            for (int c = 0; c < 8; ++c) acc[c] = (floatx4)0.0f;
            gemmT<4, 8>(acc, wsp + WS_HW1, 16, 0, hf * 8, bufB, ptb, lane);      // fused rows 0..127
            gemmRegB<4, 8>(acc, wsp + WS_HW1, 16, 4, hf * 8, fw, lane);          // f1w rows 128..255
#pragma unroll
            for (int ct = 0; ct < 8; ++ct) {
                const int ch0 = ct * 16 + g * 4;
#pragma unroll
                for (int jj = 0; jj < 4; ++jj) {                                  // scal rows 256..259
                    const float4 wj = *reinterpret_cast<const float4*>(
                        hw1 + (size_t)(256 + jj) * 256 + hf * 128 + ch0);
                    const float s = sScal[jj * 128 + pt];
                    floatx4 v = acc[ct];
                    v[0] = fmaf(wj.x, s, v[0]); v[1] = fmaf(wj.y, s, v[1]);
                    v[2] = fmaf(wj.z, s, v[2]); v[3] = fmaf(wj.w, s, v[3]);
                    acc[ct] = v;
                }
                const float4 bb = *reinterpret_cast<const float4*>(hb1 + hf * 128 + ch0);
                _Float16* dst = hf ? bufB : bufA;
                floatx4 v = acc[ct];
                storeH4(dst, pt, ch0, fmaxf(v[0] + bb.x, 0.0f), fmaxf(v[1] + bb.y, 0.0f),
                        fmaxf(v[2] + bb.z, 0.0f), fmaxf(v[3] + bb.w, 0.0f));
            }
        }
    }

    // ---------- head2 (256->128 relu): a1 lo=bufA, hi=bufB -> bufA
    {
        floatx4 acc[8];
#pragma unroll
        for (int c = 0; c < 8; ++c) acc[c] = (floatx4)0.0f;
        gemmT<4, 8>(acc, wsp + WS_HW2, 8, 0, 0, bufA, ptb, lane);
        gemmT<4, 8>(acc, wsp + WS_HW2, 8, 4, 0, bufB, ptb, lane);
        const int pt = ptb + m;
#pragma unroll
        for (int ct = 0; ct < 8; ++ct) {
            const int ch0 = ct * 16 + g * 4;
            const float4 bb = *reinterpret_cast<const float4*>(hb2 + ch0);
            floatx4 v = acc[ct];
            storeH4(bufA, pt, ch0, fmaxf(v[0] + bb.x, 0.0f), fmaxf(v[1] + bb.y, 0.0f),
                    fmaxf(v[2] + bb.z, 0.0f), fmaxf(v[3] + bb.w, 0.0f));
        }
    }

    // ---------- head3 (128->64 relu): bufA -> bufB[:,0:64]
    {
        floatx4 acc[4];
#pragma unroll
        for (int c = 0; c < 4; ++c) acc[c] = (floatx4)0.0f;
        gemmT<4, 4>(acc, wsp + WS_HW3, 4, 0, 0, bufA, ptb, lane);
        const int pt = ptb + m;
#pragma unroll
        for (int ct = 0; ct < 4; ++ct) {
            const int ch0 = ct * 16 + g * 4;
            const float4 bb = *reinterpret_cast<const float4*>(hb3 + ch0);
            floatx4 v = acc[ct];
            storeH4(bufB, pt, ch0, fmaxf(v[0] + bb.x, 0.0f), fmaxf(v[1] + bb.y, 0.0f),
                    fmaxf(v[2] + bb.z, 0.0f), fmaxf(v[3] + bb.w, 0.0f));
        }
    }
    __syncthreads();   // B7

    // ---------- head4 (64->2) fp32 + flow combine + store (threads 0..255)
    if (t < 256) {
        const int pp = t >> 1, j = t & 1;
        float d = hb4[j];
#pragma unroll
        for (int i8 = 0; i8 < 8; ++i8) {
            const int c0 = i8 * 8;
            half8 hv = *reinterpret_cast<const half8*>(bufB + pp * 128 + (c0 ^ swz(pp)));
#pragma unroll
            for (int j2 = 0; j2 < 8; ++j2)
                d = fmaf((float)hv[j2], hw4[(c0 + j2) * 2 + j], d);
        }
        const int q = qbase + pp;
        const int rem = q - b * PTS_PER_IMG;
        const int gy = rem >> 9, gx = rem & 511;
        const float flow = sCps[j * 128 + pp] + d * (j == 0 ? 512.0f : 384.0f);
        out[(((size_t)b * 2 + j) * 384 + gy) * 512 + gx] = flow;
    }
}

extern "C" void kernel_launch(void* const* d_in, const int* in_sizes, int n_in,
                              void* d_out, int out_size, void* d_ws, size_t ws_size,
                              hipStream_t stream) {
    const float* feat_s8 = (const float*)d_in[1];
    const float* feat1_s8 = (const float*)d_in[2];
    const float* feat_s16 = (const float*)d_in[3];
    const float* ctx_s8 = (const float*)d_in[4];
    const float* coarse_flow = (const float*)d_in[5];
    const float* ctx_w = (const float*)d_in[6];
    const float* ctx_b = (const float*)d_in[7];
    const float* gate1 = (const float*)d_in[8];
    const float* ffn1_w1 = (const float*)d_in[9];
    const float* ffn1_b1 = (const float*)d_in[10];
    const float* ffn1_w2 = (const float*)d_in[11];
    const float* ffn1_b2 = (const float*)d_in[12];
    const float* s8_w = (const float*)d_in[13];
    const float* s8_b = (const float*)d_in[14];
    const float* gate2 = (const float*)d_in[15];
    const float* ffn2_w1 = (const float*)d_in[16];
    const float* ffn2_b1 = (const float*)d_in[17];
    const float* ffn2_w2 = (const float*)d_in[18];
    const float* ffn2_b2 = (const float*)d_in[19];
    const float* hw1 = (const float*)d_in[20];
    const float* hb1 = (const float*)d_in[21];
    const float* hw2 = (const float*)d_in[22];
    const float* hb2 = (const float*)d_in[23];
    const float* hw3 = (const float*)d_in[24];
    const float* hb3 = (const float*)d_in[25];
    const float* hw4 = (const float*)d_in[26];
    const float* hb4 = (const float*)d_in[27];
    float* out = (float*)d_out;
    _Float16* wsp = (_Float16*)d_ws;

    prepack_kernel<<<dim3(512), dim3(64), 0, stream>>>(
        ctx_w, ffn1_w1, ffn1_w2, s8_w, ffn2_w1, ffn2_w2, hw1, hw2, hw3, wsp);

    ifd_mfma<<<dim3(NBLOCKS), dim3(512), 0, stream>>>(
        feat_s8, feat1_s8, feat_s16, ctx_s8, coarse_flow,
        ctx_b, gate1, ffn1_b1, ffn1_b2, s8_b, gate2, ffn2_b1, ffn2_b2,
        hw1, hb1, hb2, hb3, hw4, hb4, wsp, out);
}